// Round 5
// baseline (192.760 us; speedup 1.0000x reference)
//
#include <hip/hip_runtime.h>

// Problem constants (must match reference)
#define L_SZ 100000
#define K_DIM 128
#define B_SZ 16384
#define CS_SZ 8
#define NS_SZ 20
#define NEPOCH 10
#define LOG_SQRT_2PI 0.9189385332046727
#define NBLOCKS 4096

typedef float f32x4 __attribute__((ext_vector_type(4)));

// softplus(x) = max(x,0) + log(1 + exp(-|x|)); fast-math variant is fine:
// tolerance is ~2% relative on a ~2.6e7 loss.
__device__ __forceinline__ float softplus_f(float x) {
    return fmaxf(x, 0.0f) + __logf(1.0f + __expf(-fabsf(x)));
}

// ---- single fused kernel ----------------------------------------------------
// 4096 blocks x 256 threads (4 waves); one batch element per wave.
// Phase order matters: the prior sweep runs FIRST so both tables are pulled
// into L3 at sequential-HBM bandwidth; the 29 row-gathers per wave then hit
// a warm L3 instead of cold HBM at random-line efficiency.
// Lane (g, j): group g in 0..3, j in 0..15. Half-row split: lane j holds dims
// 4j..4j+3 (r0) and 64+4j..64+4j+3 (r1) -> each 64B line of a row is touched
// exactly once per gather (was twice with the interleaved layout).
// Group g owns targets n = 4s+g (n=0 is the positive target).
__global__ __launch_bounds__(256) void fused_kernel(
    const int* __restrict__ contexts, const int* __restrict__ targets,
    const int* __restrict__ neg_idx, const float* __restrict__ tW,
    const float* __restrict__ cW,
    double* __restrict__ pll, double* __restrict__ pprior,
    unsigned int* __restrict__ counter, float* __restrict__ out)
{
    const int lane = threadIdx.x & 63;
    const int wave = threadIdx.x >> 6;
    const int j = lane & 15;      // position within 16-lane group
    const int g = lane >> 4;      // group 0..3

    const int n_mine = 4 * j + g;           // target this lane softpluses
    const bool valid = (n_mine < 21);
    const float sgn = (n_mine == 0) ? -1.0f : 1.0f;  // pos: softplus(-eta)

    // wave-uniform batch index -> SGPR so uniform index loads become s_load
    const int b = __builtin_amdgcn_readfirstlane(blockIdx.x * 4 + wave);

    // ---- resolve indices early: tiny loads, in flight during the sweep -----
    int ctxi[CS_SZ];
    #pragma unroll
    for (int c = 0; c < CS_SZ; ++c) ctxi[c] = contexts[b * CS_SZ + c];

    int tidx[6];
    #pragma unroll
    for (int s = 0; s < 6; ++s) {
        const int n = 4 * s + g;
        int t;
        if (n == 0)       t = targets[b];
        else if (n < 21)  t = neg_idx[b * NS_SZ + (n - 1)];
        else              t = neg_idx[b * NS_SZ];   // clamped, masked later
        tidx[s] = t;
    }

    // ---- phase 1: prior sweep (sum of squares; also warms L3) --------------
    const int NT4 = (L_SZ * K_DIM) / 4;          // 3,200,000
    const int NC4 = ((L_SZ + 1) * K_DIM) / 4;    // 3,200,032
    const int tid = blockIdx.x * blockDim.x + threadIdx.x;
    const int stride = gridDim.x * blockDim.x;

    float pacc = 0.0f;
    const f32x4* t4 = reinterpret_cast<const f32x4*>(tW);
    for (int i = tid; i < NT4; i += stride) {
        const f32x4 v = t4[i];
        pacc += v.x * v.x + v.y * v.y + v.z * v.z + v.w * v.w;
    }
    const f32x4* c4 = reinterpret_cast<const f32x4*>(cW);
    for (int i = tid; i < NC4; i += stride) {
        const f32x4 v = c4[i];
        pacc += v.x * v.x + v.y * v.y + v.z * v.z + v.w * v.w;
    }

    // ---- phase 2: gathers against warm L3 -----------------------------------
    float4 r0[6], r1[6];
    #pragma unroll
    for (int s = 0; s < 6; ++s) {
        const float* base = &tW[(size_t)tidx[s] * K_DIM];
        r0[s] = *reinterpret_cast<const float4*>(base + 4 * j);
        r1[s] = *reinterpret_cast<const float4*>(base + 64 + 4 * j);
    }

    float4 s0 = {0.f, 0.f, 0.f, 0.f}, s1 = {0.f, 0.f, 0.f, 0.f};
    #pragma unroll
    for (int c = 0; c < CS_SZ; ++c) {
        const float* base = &cW[(size_t)ctxi[c] * K_DIM];
        const float4 a = *reinterpret_cast<const float4*>(base + 4 * j);
        const float4 d = *reinterpret_cast<const float4*>(base + 64 + 4 * j);
        s0.x += a.x; s0.y += a.y; s0.z += a.z; s0.w += a.w;
        s1.x += d.x; s1.y += d.y; s1.z += d.z; s1.w += d.w;
    }

    // ---- 6 dot products + 16-lane butterflies ------------------------------
    float keep = 0.0f;
    #pragma unroll
    for (int s = 0; s < 6; ++s) {
        const float4 a = r0[s], d = r1[s];
        float p = a.x * s0.x + a.y * s0.y + a.z * s0.z + a.w * s0.w
                + d.x * s1.x + d.y * s1.y + d.z * s1.z + d.w * s1.w;
        p += __shfl_xor(p, 1, 16);
        p += __shfl_xor(p, 2, 16);
        p += __shfl_xor(p, 4, 16);
        p += __shfl_xor(p, 8, 16);
        keep = (j == s) ? p : keep;
    }
    float lacc = valid ? softplus_f(sgn * keep) : 0.0f;

    // ---- per-wave then per-block reduction ---------------------------------
    #pragma unroll
    for (int o = 32; o; o >>= 1) {
        lacc += __shfl_xor(lacc, o, 64);
        pacc += __shfl_xor(pacc, o, 64);
    }
    __shared__ float sl[4], sp[4];
    if (lane == 0) { sl[wave] = lacc; sp[wave] = pacc; }
    __syncthreads();

    // ---- last-block finalize (threadfence + ticket) -------------------------
    __shared__ bool amLast;
    if (threadIdx.x == 0) {
        pll[blockIdx.x]    = (double)(sl[0] + sl[1] + sl[2] + sl[3]);
        pprior[blockIdx.x] = (double)(sp[0] + sp[1] + sp[2] + sp[3]);
        __threadfence();                       // release partial writes
        const unsigned t = atomicAdd(counter, 1u);
        amLast = (t == (unsigned)(gridDim.x - 1));
    }
    __syncthreads();

    if (amLast) {
        __threadfence();                       // acquire all partials
        double a = 0.0, p = 0.0;
        for (int i = threadIdx.x; i < NBLOCKS; i += 256) {
            a += pll[i];
            p += pprior[i];
        }
        __shared__ double sA[256], sP[256];
        sA[threadIdx.x] = a; sP[threadIdx.x] = p;
        __syncthreads();
        for (int s = 128; s > 0; s >>= 1) {
            if (threadIdx.x < s) {
                sA[threadIdx.x] += sA[threadIdx.x + s];
                sP[threadIdx.x] += sP[threadIdx.x + s];
            }
            __syncthreads();
        }
        if (threadIdx.x == 0) {
            // loss = NEPOCH*sum(softplus) + 0.5*sum(x^2) + count*LOG_SQRT_2PI
            const double C = (double)((2LL * L_SZ + 1) * K_DIM) * LOG_SQRT_2PI;
            out[0] = (float)((double)NEPOCH * sA[0] + 0.5 * sP[0] + C);
        }
    }
}

extern "C" void kernel_launch(void* const* d_in, const int* in_sizes, int n_in,
                              void* d_out, int out_size, void* d_ws, size_t ws_size,
                              hipStream_t stream) {
    const int*   contexts = (const int*)d_in[0];
    const int*   targets  = (const int*)d_in[1];
    const int*   neg_idx  = (const int*)d_in[2];
    const float* tW       = (const float*)d_in[3];
    const float* cW       = (const float*)d_in[4];
    float* out = (float*)d_out;

    double* pll        = (double*)d_ws;          // NBLOCKS doubles
    double* pprior     = pll + NBLOCKS;          // NBLOCKS doubles
    unsigned* counter  = (unsigned*)(pprior + NBLOCKS);

    // reset the ticket counter every call (graph-capture legal)
    hipMemsetAsync(counter, 0, sizeof(unsigned), stream);

    fused_kernel<<<NBLOCKS, 256, 0, stream>>>(contexts, targets, neg_idx,
                                              tW, cW, pll, pprior, counter, out);
}

// Round 6
// 62.843 us; speedup vs baseline: 3.0673x; 3.0673x over previous
//
#include <hip/hip_runtime.h>

// Problem constants (must match reference)
#define L_SZ 100000
#define K_DIM 128
#define B_SZ 16384
#define CS_SZ 8
#define NS_SZ 20
#define NEPOCH 10
#define LOG_SQRT_2PI 0.9189385332046727
#define NBLOCKS 4096

typedef float f32x4 __attribute__((ext_vector_type(4)));

// softplus(x) = max(x,0) + log(1 + exp(-|x|)); fast-math variant is fine:
// tolerance is ~2% relative on a ~2.6e7 loss.
__device__ __forceinline__ float softplus_f(float x) {
    return fmaxf(x, 0.0f) + __logf(1.0f + __expf(-fabsf(x)));
}

// ---- fused likelihood + prior kernel ---------------------------------------
// 4096 blocks x 256 threads (4 waves); one batch element per wave.
// NOTE: no nontemporal loads anywhere — both weight tables (102 MB) stay
// resident in the 256 MB L3 across graph replays, so the steady-state is
// L3-bound, not HBM-bound (verified R5: replay FETCH_SIZE = 0.4 MB).
// Lane (g, j): group g in 0..3, j in 0..15. Half-row split: lane j holds dims
// 4j..4j+3 (r0) and 64+4j..64+4j+3 (r1) -> each 64B line of a row touched once.
// Group g owns targets n = 4s+g (n=0 is the positive target).
// Gathers are issued BEFORE the prior sweep so the sweep's independent
// streaming work hides the gather latency.
__global__ __launch_bounds__(256) void fused_kernel(
    const int* __restrict__ contexts, const int* __restrict__ targets,
    const int* __restrict__ neg_idx, const float* __restrict__ tW,
    const float* __restrict__ cW,
    double* __restrict__ pll, double* __restrict__ pprior)
{
    const int lane = threadIdx.x & 63;
    const int wave = threadIdx.x >> 6;
    const int j = lane & 15;      // position within 16-lane group
    const int g = lane >> 4;      // group 0..3

    const int n_mine = 4 * j + g;           // target this lane softpluses
    const bool valid = (n_mine < 21);
    const float sgn = (n_mine == 0) ? -1.0f : 1.0f;  // pos: softplus(-eta)

    // wave-uniform batch index -> SGPR so uniform index loads become s_load
    const int b = __builtin_amdgcn_readfirstlane(blockIdx.x * 4 + wave);

    // ---- resolve indices (scalar loads, wave-uniform) ----------------------
    int ctxi[CS_SZ];
    #pragma unroll
    for (int c = 0; c < CS_SZ; ++c) ctxi[c] = contexts[b * CS_SZ + c];

    int tidx[6];
    #pragma unroll
    for (int s = 0; s < 6; ++s) {
        const int n = 4 * s + g;
        int t;
        if (n == 0)       t = targets[b];
        else if (n < 21)  t = neg_idx[b * NS_SZ + (n - 1)];
        else              t = neg_idx[b * NS_SZ];   // clamped, masked later
        tidx[s] = t;
    }

    // ---- ctx_sum gathers (8 rows) ------------------------------------------
    float4 s0 = {0.f, 0.f, 0.f, 0.f}, s1 = {0.f, 0.f, 0.f, 0.f};
    #pragma unroll
    for (int c = 0; c < CS_SZ; ++c) {
        const float* base = &cW[(size_t)ctxi[c] * K_DIM];
        const float4 a = *reinterpret_cast<const float4*>(base + 4 * j);
        const float4 d = *reinterpret_cast<const float4*>(base + 64 + 4 * j);
        s0.x += a.x; s0.y += a.y; s0.z += a.z; s0.w += a.w;
        s1.x += d.x; s1.y += d.y; s1.z += d.z; s1.w += d.w;
    }

    // ---- target gathers + dots + 16-lane butterflies -----------------------
    float keep = 0.0f;
    #pragma unroll
    for (int s = 0; s < 6; ++s) {
        const float* base = &tW[(size_t)tidx[s] * K_DIM];
        const float4 a = *reinterpret_cast<const float4*>(base + 4 * j);
        const float4 d = *reinterpret_cast<const float4*>(base + 64 + 4 * j);
        float p = a.x * s0.x + a.y * s0.y + a.z * s0.z + a.w * s0.w
                + d.x * s1.x + d.y * s1.y + d.z * s1.z + d.w * s1.w;
        p += __shfl_xor(p, 1, 16);
        p += __shfl_xor(p, 2, 16);
        p += __shfl_xor(p, 4, 16);
        p += __shfl_xor(p, 8, 16);
        keep = (j == s) ? p : keep;
    }
    float lacc = valid ? softplus_f(sgn * keep) : 0.0f;

    // ---- prior sweep: grid-stride sum of squares over both tables ----------
    const int NT4 = (L_SZ * K_DIM) / 4;          // 3,200,000
    const int NC4 = ((L_SZ + 1) * K_DIM) / 4;    // 3,200,032
    const int tid = blockIdx.x * blockDim.x + threadIdx.x;
    const int stride = gridDim.x * blockDim.x;

    float pacc = 0.0f;
    const f32x4* t4 = reinterpret_cast<const f32x4*>(tW);
    for (int i = tid; i < NT4; i += stride) {
        const f32x4 v = t4[i];
        pacc += v.x * v.x + v.y * v.y + v.z * v.z + v.w * v.w;
    }
    const f32x4* c4 = reinterpret_cast<const f32x4*>(cW);
    for (int i = tid; i < NC4; i += stride) {
        const f32x4 v = c4[i];
        pacc += v.x * v.x + v.y * v.y + v.z * v.z + v.w * v.w;
    }

    // ---- per-wave then per-block reduction ---------------------------------
    #pragma unroll
    for (int o = 32; o; o >>= 1) {
        lacc += __shfl_xor(lacc, o, 64);
        pacc += __shfl_xor(pacc, o, 64);
    }
    __shared__ float sl[4], sp[4];
    if (lane == 0) { sl[wave] = lacc; sp[wave] = pacc; }
    __syncthreads();
    if (threadIdx.x == 0) {
        pll[blockIdx.x]    = (double)(sl[0] + sl[1] + sl[2] + sl[3]);
        pprior[blockIdx.x] = (double)(sp[0] + sp[1] + sp[2] + sp[3]);
    }
}

// ---- finalize: reduce partials, assemble scalar loss ------------------------
__global__ __launch_bounds__(256) void finalize_kernel(
    const double* __restrict__ pll, int nll,
    const double* __restrict__ pprior, int nprior,
    float* __restrict__ out)
{
    double a = 0.0, p = 0.0;
    for (int i = threadIdx.x; i < nll; i += 256) a += pll[i];
    for (int i = threadIdx.x; i < nprior; i += 256) p += pprior[i];

    __shared__ double sA[256], sP[256];
    sA[threadIdx.x] = a; sP[threadIdx.x] = p;
    __syncthreads();
    for (int s = 128; s > 0; s >>= 1) {
        if (threadIdx.x < s) {
            sA[threadIdx.x] += sA[threadIdx.x + s];
            sP[threadIdx.x] += sP[threadIdx.x + s];
        }
        __syncthreads();
    }
    if (threadIdx.x == 0) {
        // loss = NEPOCH*sum(softplus) + 0.5*sum(x^2) + count*LOG_SQRT_2PI
        const double C = (double)((2LL * L_SZ + 1) * K_DIM) * LOG_SQRT_2PI;
        const double loss = (double)NEPOCH * sA[0] + 0.5 * sP[0] + C;
        out[0] = (float)loss;
    }
}

extern "C" void kernel_launch(void* const* d_in, const int* in_sizes, int n_in,
                              void* d_out, int out_size, void* d_ws, size_t ws_size,
                              hipStream_t stream) {
    const int*   contexts = (const int*)d_in[0];
    const int*   targets  = (const int*)d_in[1];
    const int*   neg_idx  = (const int*)d_in[2];
    const float* tW       = (const float*)d_in[3];
    const float* cW       = (const float*)d_in[4];
    float* out = (float*)d_out;

    double* pll    = (double*)d_ws;          // NBLOCKS doubles
    double* pprior = pll + NBLOCKS;          // NBLOCKS doubles

    fused_kernel<<<NBLOCKS, 256, 0, stream>>>(contexts, targets, neg_idx,
                                              tW, cW, pll, pprior);
    finalize_kernel<<<1, 256, 0, stream>>>(pll, NBLOCKS, pprior, NBLOCKS, out);
}

// Round 7
// 61.927 us; speedup vs baseline: 3.1127x; 1.0148x over previous
//
#include <hip/hip_runtime.h>

// Problem constants (must match reference)
#define L_SZ 100000
#define K_DIM 128
#define B_SZ 16384
#define CS_SZ 8
#define NS_SZ 20
#define NEPOCH 10
#define LOG_SQRT_2PI 0.9189385332046727
#define NBLOCKS 4096

typedef float f32x4 __attribute__((ext_vector_type(4)));

// softplus(x) = max(x,0) + log(1 + exp(-|x|)); fast-math variant is fine:
// tolerance is ~2% relative on a ~2.6e7 loss.
__device__ __forceinline__ float softplus_f(float x) {
    return fmaxf(x, 0.0f) + __logf(1.0f + __expf(-fabsf(x)));
}

// ---- fused likelihood + prior kernel ---------------------------------------
// 4096 blocks x 256 threads (4 waves); one batch element per wave.
// PHASE ORDER IS THE POINT: every wave runs the prior sweep FIRST. The sweep
// collectively streams both tables (104 MB < 256 MB Infinity Cache) at
// sequential HBM bandwidth; the random row-gathers then run against a warm
// IC instead of paying cold-HBM random-line efficiency. (R6 measured: with
// gathers first, every dispatch re-fetches 163 MB at only 3.2 TB/s.)
// Lane (g, j): group g in 0..3, j in 0..15. Half-row split: lane j holds dims
// 4j..4j+3 and 64+4j..64+4j+3 -> each 64B line of a row touched exactly once.
// Group g owns targets n = 4s+g (n=0 is the positive target); the 3 slots
// with n>=21 are exec-masked off (no wasted gathers).
__global__ __launch_bounds__(256, 8) void fused_kernel(
    const int* __restrict__ contexts, const int* __restrict__ targets,
    const int* __restrict__ neg_idx, const float* __restrict__ tW,
    const float* __restrict__ cW,
    double* __restrict__ pll, double* __restrict__ pprior)
{
    const int lane = threadIdx.x & 63;
    const int wave = threadIdx.x >> 6;
    const int j = lane & 15;      // position within 16-lane group
    const int g = lane >> 4;      // group 0..3

    const int n_mine = 4 * j + g;           // target this lane softpluses
    const bool valid = (n_mine < 21);
    const float sgn = (n_mine == 0) ? -1.0f : 1.0f;  // pos: softplus(-eta)

    // wave-uniform batch index -> SGPR so uniform index loads become s_load
    const int b = __builtin_amdgcn_readfirstlane(blockIdx.x * 4 + wave);

    // ---- resolve indices up front (tiny loads; latency hidden by the sweep)
    int ctxi[CS_SZ];
    #pragma unroll
    for (int c = 0; c < CS_SZ; ++c) ctxi[c] = contexts[b * CS_SZ + c];

    int tidx[6];
    #pragma unroll
    for (int s = 0; s < 6; ++s) {
        const int n = 4 * s + g;
        int t = 0;
        if (n == 0)       t = targets[b];
        else if (n < 21)  t = neg_idx[b * NS_SZ + (n - 1)];
        tidx[s] = t;
    }

    // ---- phase 1: prior sweep (sum of squares; collectively warms the IC) --
    const int NT4 = (L_SZ * K_DIM) / 4;          // 3,200,000
    const int NC4 = ((L_SZ + 1) * K_DIM) / 4;    // 3,200,032
    const int tid = blockIdx.x * blockDim.x + threadIdx.x;
    const int stride = gridDim.x * blockDim.x;

    float pacc = 0.0f;
    const f32x4* t4 = reinterpret_cast<const f32x4*>(tW);
    for (int i = tid; i < NT4; i += stride) {
        const f32x4 v = t4[i];
        pacc += v.x * v.x + v.y * v.y + v.z * v.z + v.w * v.w;
    }
    const f32x4* c4 = reinterpret_cast<const f32x4*>(cW);
    for (int i = tid; i < NC4; i += stride) {
        const f32x4 v = c4[i];
        pacc += v.x * v.x + v.y * v.y + v.z * v.z + v.w * v.w;
    }

    // ---- phase 2: ctx_sum gathers (8 rows, warm IC) ------------------------
    float4 s0 = {0.f, 0.f, 0.f, 0.f}, s1 = {0.f, 0.f, 0.f, 0.f};
    #pragma unroll
    for (int c = 0; c < CS_SZ; ++c) {
        const float* base = &cW[(size_t)ctxi[c] * K_DIM];
        const float4 a = *reinterpret_cast<const float4*>(base + 4 * j);
        const float4 d = *reinterpret_cast<const float4*>(base + 64 + 4 * j);
        s0.x += a.x; s0.y += a.y; s0.z += a.z; s0.w += a.w;
        s1.x += d.x; s1.y += d.y; s1.z += d.z; s1.w += d.w;
    }

    // ---- target gathers + dots + 16-lane butterflies -----------------------
    float keep = 0.0f;
    #pragma unroll
    for (int s = 0; s < 6; ++s) {
        float p = 0.0f;
        if (4 * s + g < 21) {               // exec-masked: no wasted gathers
            const float* base = &tW[(size_t)tidx[s] * K_DIM];
            const float4 a = *reinterpret_cast<const float4*>(base + 4 * j);
            const float4 d = *reinterpret_cast<const float4*>(base + 64 + 4 * j);
            p = a.x * s0.x + a.y * s0.y + a.z * s0.z + a.w * s0.w
              + d.x * s1.x + d.y * s1.y + d.z * s1.z + d.w * s1.w;
        }
        p += __shfl_xor(p, 1, 16);
        p += __shfl_xor(p, 2, 16);
        p += __shfl_xor(p, 4, 16);
        p += __shfl_xor(p, 8, 16);
        keep = (j == s) ? p : keep;
    }
    float lacc = valid ? softplus_f(sgn * keep) : 0.0f;

    // ---- per-wave then per-block reduction ---------------------------------
    #pragma unroll
    for (int o = 32; o; o >>= 1) {
        lacc += __shfl_xor(lacc, o, 64);
        pacc += __shfl_xor(pacc, o, 64);
    }
    __shared__ float sl[4], sp[4];
    if (lane == 0) { sl[wave] = lacc; sp[wave] = pacc; }
    __syncthreads();
    if (threadIdx.x == 0) {
        pll[blockIdx.x]    = (double)(sl[0] + sl[1] + sl[2] + sl[3]);
        pprior[blockIdx.x] = (double)(sp[0] + sp[1] + sp[2] + sp[3]);
    }
}

// ---- finalize: reduce partials, assemble scalar loss ------------------------
__global__ __launch_bounds__(256) void finalize_kernel(
    const double* __restrict__ pll, int nll,
    const double* __restrict__ pprior, int nprior,
    float* __restrict__ out)
{
    double a = 0.0, p = 0.0;
    for (int i = threadIdx.x; i < nll; i += 256) a += pll[i];
    for (int i = threadIdx.x; i < nprior; i += 256) p += pprior[i];

    __shared__ double sA[256], sP[256];
    sA[threadIdx.x] = a; sP[threadIdx.x] = p;
    __syncthreads();
    for (int s = 128; s > 0; s >>= 1) {
        if (threadIdx.x < s) {
            sA[threadIdx.x] += sA[threadIdx.x + s];
            sP[threadIdx.x] += sP[threadIdx.x + s];
        }
        __syncthreads();
    }
    if (threadIdx.x == 0) {
        // loss = NEPOCH*sum(softplus) + 0.5*sum(x^2) + count*LOG_SQRT_2PI
        const double C = (double)((2LL * L_SZ + 1) * K_DIM) * LOG_SQRT_2PI;
        const double loss = (double)NEPOCH * sA[0] + 0.5 * sP[0] + C;
        out[0] = (float)loss;
    }
}

extern "C" void kernel_launch(void* const* d_in, const int* in_sizes, int n_in,
                              void* d_out, int out_size, void* d_ws, size_t ws_size,
                              hipStream_t stream) {
    const int*   contexts = (const int*)d_in[0];
    const int*   targets  = (const int*)d_in[1];
    const int*   neg_idx  = (const int*)d_in[2];
    const float* tW       = (const float*)d_in[3];
    const float* cW       = (const float*)d_in[4];
    float* out = (float*)d_out;

    double* pll    = (double*)d_ws;          // NBLOCKS doubles
    double* pprior = pll + NBLOCKS;          // NBLOCKS doubles

    fused_kernel<<<NBLOCKS, 256, 0, stream>>>(contexts, targets, neg_idx,
                                              tW, cW, pll, pprior);
    finalize_kernel<<<1, 256, 0, stream>>>(pll, NBLOCKS, pprior, NBLOCKS, out);
}